// Round 4
// baseline (345.030 us; speedup 1.0000x reference)
//
#include <hip/hip_runtime.h>

#define IN_F 128
#define OUT_F 64
#define NEG 0.01f
#define LDSP 132  // padded row stride (floats)

__device__ __forceinline__ float leaky_exp(float e) {
    e = (e >= 0.f) ? e : NEG * e;
    return expf(e);
}

// --- Kernel 1: msg = x @ W.T (tiled, 64x64 per block, full K=128)
// fused alpha[n]=msg[n].a[:64], beta[n]=msg[n].a[64:]
__global__ __launch_bounds__(256) void gemm_msg_kernel(
    const float* __restrict__ x, const float* __restrict__ W,
    const float* __restrict__ a,
    float* __restrict__ msg, float* __restrict__ alpha, float* __restrict__ beta,
    int N)
{
    __shared__ float xs[64 * LDSP];
    __shared__ float Ws[64 * LDSP];
    const int tid = threadIdx.x;
    const int base = blockIdx.x * 64;

#pragma unroll
    for (int t = 0; t < 8; ++t) {
        int i = tid + t * 256;
        int c = i >> 5;
        int k4 = i & 31;
        float4 wv = ((const float4*)W)[i];
        *(float4*)&Ws[c * LDSP + k4 * 4] = wv;
    }
#pragma unroll
    for (int t = 0; t < 8; ++t) {
        int i = tid + t * 256;
        int r = i >> 5;
        int k4 = i & 31;
        int row = base + r;
        float4 xv = make_float4(0.f, 0.f, 0.f, 0.f);
        if (row < N) xv = ((const float4*)x)[(size_t)row * (IN_F / 4) + k4];
        *(float4*)&xs[r * LDSP + k4 * 4] = xv;
    }
    __syncthreads();

    const int tx = tid & 15;
    const int ty = tid >> 4;
    const float* xrow = &xs[(ty * 4) * LDSP];
    const float* wrow = &Ws[(tx * 4) * LDSP];

    float acc[4][4] = {};
    for (int k = 0; k < IN_F; k += 4) {
        float4 xv[4], wv[4];
#pragma unroll
        for (int i = 0; i < 4; ++i) xv[i] = *(const float4*)&xrow[i * LDSP + k];
#pragma unroll
        for (int i = 0; i < 4; ++i) wv[i] = *(const float4*)&wrow[i * LDSP + k];
#pragma unroll
        for (int ri = 0; ri < 4; ++ri)
#pragma unroll
            for (int ci = 0; ci < 4; ++ci) {
                acc[ri][ci] += xv[ri].x * wv[ci].x;
                acc[ri][ci] += xv[ri].y * wv[ci].y;
                acc[ri][ci] += xv[ri].z * wv[ci].z;
                acc[ri][ci] += xv[ri].w * wv[ci].w;
            }
    }

    float a_lo[4], a_hi[4];
#pragma unroll
    for (int ci = 0; ci < 4; ++ci) {
        a_lo[ci] = a[tx * 4 + ci];
        a_hi[ci] = a[OUT_F + tx * 4 + ci];
    }

#pragma unroll
    for (int ri = 0; ri < 4; ++ri) {
        int row = base + ty * 4 + ri;
        if (row < N) {
            *(float4*)&msg[(size_t)row * OUT_F + tx * 4] =
                make_float4(acc[ri][0], acc[ri][1], acc[ri][2], acc[ri][3]);
        }
        float pa = acc[ri][0] * a_lo[0] + acc[ri][1] * a_lo[1] +
                   acc[ri][2] * a_lo[2] + acc[ri][3] * a_lo[3];
        float pb = acc[ri][0] * a_hi[0] + acc[ri][1] * a_hi[1] +
                   acc[ri][2] * a_hi[2] + acc[ri][3] * a_hi[3];
#pragma unroll
        for (int off = 1; off < 16; off <<= 1) {
            pa += __shfl_xor(pa, off);
            pb += __shfl_xor(pb, off);
        }
        if (tx == 0 && row < N) { alpha[row] = pa; beta[row] = pb; }
    }
}

// --- Kernel 2: in-degree histogram, 4 edges/thread via int4 ---
__global__ __launch_bounds__(256) void count_kernel(
    const int* __restrict__ dst, int* __restrict__ cnt, int E)
{
    const int base = (blockIdx.x * 256 + threadIdx.x) * 4;
    if (base + 3 < E) {
        int4 d4 = *(const int4*)(dst + base);
        atomicAdd(&cnt[d4.x], 1);
        atomicAdd(&cnt[d4.y], 1);
        atomicAdd(&cnt[d4.z], 1);
        atomicAdd(&cnt[d4.w], 1);
    } else {
        for (int e = base; e < E; ++e) atomicAdd(&cnt[dst[e]], 1);
    }
}

// --- Scan (hierarchical) ---
__global__ __launch_bounds__(1024) void scan1_kernel(
    const int* __restrict__ cnt, int* __restrict__ offs, int* __restrict__ bsum, int N)
{
    __shared__ int tmp[1024];
    int t = threadIdx.x;
    int i = blockIdx.x * 1024 + t;
    int v = (i < N) ? cnt[i] : 0;
    tmp[t] = v; __syncthreads();
#pragma unroll
    for (int d = 1; d < 1024; d <<= 1) {
        int add = (t >= d) ? tmp[t - d] : 0;
        __syncthreads();
        tmp[t] += add;
        __syncthreads();
    }
    if (i < N) offs[i] = tmp[t] - v;
    if (t == 1023) bsum[blockIdx.x] = tmp[t];
}

__global__ __launch_bounds__(128) void scan2_kernel(
    const int* __restrict__ bsum, int* __restrict__ bscan, int NB)
{
    __shared__ int tmp[128];
    int t = threadIdx.x;
    int v = (t < NB) ? bsum[t] : 0;
    tmp[t] = v; __syncthreads();
#pragma unroll
    for (int d = 1; d < 128; d <<= 1) {
        int add = (t >= d) ? tmp[t - d] : 0;
        __syncthreads();
        tmp[t] += add;
        __syncthreads();
    }
    if (t < NB) bscan[t] = tmp[t] - v;
}

__global__ __launch_bounds__(1024) void scan3_kernel(
    int* __restrict__ offs, int* __restrict__ cursor,
    const int* __restrict__ bscan, int N, int E)
{
    int i = blockIdx.x * 1024 + threadIdx.x;
    if (i < N) {
        int o = offs[i] + bscan[blockIdx.x];
        offs[i] = o;
        cursor[i] = o;
    }
    if (i == 0) offs[N] = E;
}

// --- Kernel 3: bucket edges by dst, fused {src,w} int2 scatter, 4 edges/thread ---
__global__ __launch_bounds__(256) void fill_kernel(
    const int* __restrict__ src, const int* __restrict__ dst,
    const float* __restrict__ alpha, const float* __restrict__ beta,
    int* __restrict__ cursor, int2* __restrict__ edges, int E)
{
    const int base = (blockIdx.x * 256 + threadIdx.x) * 4;
    if (base + 3 < E) {
        int4 s4 = *(const int4*)(src + base);
        int4 d4 = *(const int4*)(dst + base);
        // 4 independent gather+atomic+scatter chains in flight
        float b0 = beta[s4.x], b1 = beta[s4.y], b2 = beta[s4.z], b3 = beta[s4.w];
        float a0 = alpha[d4.x], a1 = alpha[d4.y], a2 = alpha[d4.z], a3 = alpha[d4.w];
        float w0 = leaky_exp(a0 + b0);
        float w1 = leaky_exp(a1 + b1);
        float w2 = leaky_exp(a2 + b2);
        float w3 = leaky_exp(a3 + b3);
        int p0 = atomicAdd(&cursor[d4.x], 1);
        int p1 = atomicAdd(&cursor[d4.y], 1);
        int p2 = atomicAdd(&cursor[d4.z], 1);
        int p3 = atomicAdd(&cursor[d4.w], 1);
        edges[p0] = make_int2(s4.x, __float_as_int(w0));
        edges[p1] = make_int2(s4.y, __float_as_int(w1));
        edges[p2] = make_int2(s4.z, __float_as_int(w2));
        edges[p3] = make_int2(s4.w, __float_as_int(w3));
    } else {
        for (int e = base; e < E; ++e) {
            int s = src[e], d = dst[e];
            float w = leaky_exp(alpha[d] + beta[s]);
            int pos = atomicAdd(&cursor[d], 1);
            edges[pos] = make_int2(s, __float_as_int(w));
        }
    }
}

// --- Kernel 4: per-node aggregation (no atomics), self-loop + normalize fused ---
__global__ __launch_bounds__(256) void aggregate_kernel(
    const int* __restrict__ offs, const int2* __restrict__ edges,
    const float* __restrict__ msg,
    const float* __restrict__ alpha, const float* __restrict__ beta,
    float* __restrict__ out, int N)
{
    const int node = blockIdx.x * 4 + (threadIdx.x >> 6);
    if (node >= N) return;
    const int lane = threadIdx.x & 63;

    const float ws = leaky_exp(alpha[node] + beta[node]);  // self-loop
    float acc = ws * msg[(size_t)node * OUT_F + lane];
    float den = ws;

    const int st = offs[node], en = offs[node + 1];
    int j = st;
    for (; j + 3 < en; j += 4) {
        int2 e0 = edges[j + 0], e1 = edges[j + 1];
        int2 e2 = edges[j + 2], e3 = edges[j + 3];
        float w0 = __int_as_float(e0.y), w1 = __int_as_float(e1.y);
        float w2 = __int_as_float(e2.y), w3 = __int_as_float(e3.y);
        float m0 = msg[(size_t)e0.x * OUT_F + lane];
        float m1 = msg[(size_t)e1.x * OUT_F + lane];
        float m2 = msg[(size_t)e2.x * OUT_F + lane];
        float m3 = msg[(size_t)e3.x * OUT_F + lane];
        acc += w0 * m0; acc += w1 * m1; acc += w2 * m2; acc += w3 * m3;
        den += w0 + w1 + w2 + w3;
    }
    for (; j < en; ++j) {
        int2 e = edges[j];
        float w = __int_as_float(e.y);
        acc += w * msg[(size_t)e.x * OUT_F + lane];
        den += w;
    }
    out[(size_t)node * OUT_F + lane] = acc / fmaxf(den, 1e-6f);
}

extern "C" void kernel_launch(void* const* d_in, const int* in_sizes, int n_in,
                              void* d_out, int out_size, void* d_ws, size_t ws_size,
                              hipStream_t stream) {
    const float* x  = (const float*)d_in[0];
    const float* W  = (const float*)d_in[1];
    const float* a  = (const float*)d_in[2];
    const int*   ei = (const int*)d_in[3];
    float* out = (float*)d_out;

    const int IN = in_sizes[1] / OUT_F;   // 128
    const int N  = in_sizes[0] / IN;      // 100000
    const int E  = in_sizes[3] / 2;       // 1600000
    const int NB = (N + 1023) / 1024;

    char* p = (char*)d_ws;
    float* msg    = (float*)p; p += (size_t)N * OUT_F * 4;
    float* alpha  = (float*)p; p += (size_t)N * 4;
    float* beta   = (float*)p; p += (size_t)N * 4;
    int*   cnt    = (int*)p;   p += (size_t)N * 4;
    int*   offs   = (int*)p;   p += (size_t)(N + 1) * 4;
    int*   cursor = (int*)p;   p += (size_t)N * 4;
    int*   bsum   = (int*)p;   p += (size_t)NB * 4;
    int*   bscan  = (int*)p;   p += (size_t)NB * 4;
    int2*  edges  = (int2*)p;  p += (size_t)E * 8;

    const int* esrc = ei;
    const int* edst = ei + E;

    hipMemsetAsync(cnt, 0, (size_t)N * 4, stream);

    gemm_msg_kernel<<<(N + 63) / 64, 256, 0, stream>>>(x, W, a, msg, alpha, beta, N);
    count_kernel<<<(E / 4 + 255) / 256, 256, 0, stream>>>(edst, cnt, E);
    scan1_kernel<<<NB, 1024, 0, stream>>>(cnt, offs, bsum, N);
    scan2_kernel<<<1, 128, 0, stream>>>(bsum, bscan, NB);
    scan3_kernel<<<NB, 1024, 0, stream>>>(offs, cursor, bscan, N, E);
    fill_kernel<<<(E / 4 + 255) / 256, 256, 0, stream>>>(esrc, edst, alpha, beta,
                                                         cursor, edges, E);
    aggregate_kernel<<<(N + 3) / 4, 256, 0, stream>>>(offs, edges, msg,
                                                      alpha, beta, out, N);
}